// Round 7
// baseline (191.630 us; speedup 1.0000x reference)
//
#include <hip/hip_runtime.h>
#include <hip/hip_bf16.h>
#include <math.h>

#define TT 2048
typedef __bf16 bf16x8 __attribute__((ext_vector_type(8)));
typedef float f32x4 __attribute__((ext_vector_type(4)));
typedef __hip_bfloat16 bf16;

static __device__ __forceinline__ f32x4 mfma16(bf16x8 a, bf16x8 b, f32x4 c) {
  return __builtin_amdgcn_mfma_f32_16x16x32_bf16(a, b, c, 0, 0, 0);
}
static __device__ __forceinline__ bf16x8 ldb8(const bf16* p) {
  return *(const bf16x8*)p;
}
// async global->LDS, 16B per lane; lds base must be wave-uniform (HW adds lane*16)
static __device__ __forceinline__ void gll16(const bf16* g, bf16* l) {
  __builtin_amdgcn_global_load_lds(
      (const __attribute__((address_space(1))) unsigned int*)g,
      (__attribute__((address_space(3))) unsigned int*)l, 16, 0, 0);
}

// ---------------- fused weight convert/pack + attn RMSNorm ----------------
__global__ void __launch_bounds__(256) prep_kernel(
    const float* __restrict__ wq, const float* __restrict__ wk,
    const float* __restrict__ wv, const float* __restrict__ wo,
    const float* __restrict__ wg, const float* __restrict__ wu,
    const float* __restrict__ wd,
    bf16* __restrict__ Wqkv, bf16* __restrict__ Wo,
    bf16* __restrict__ Wgu, bf16* __restrict__ Wd,
    const float* __restrict__ x, const float* __restrict__ rmsw,
    bf16* __restrict__ hb) {
  if (blockIdx.x < 4096) {
    int idx = blockIdx.x * 256 + threadIdx.x;  // 0 .. 1048575
    if (idx < 196608) {                        // QKV pack
      int row = idx >> 8, col = idx & 255;
      const float* src = row < 256 ? wq : (row < 512 ? wk : wv);
      Wqkv[idx] = __float2bfloat16(src[(row & 255) * 256 + col]);
    } else if (idx < 262144) {
      int i = idx - 196608;
      Wo[i] = __float2bfloat16(wo[i]);
    } else if (idx < 786432) {                 // gate/up interleaved per 16 rows
      int i = idx - 262144;
      int row = i >> 8, col = i & 255;
      int t = row >> 4, r = row & 15;
      int f = (t >> 1) * 16 + r;
      const float* src = (t & 1) ? wu : wg;
      Wgu[i] = __float2bfloat16(src[f * 256 + col]);
    } else {
      int i = idx - 786432;
      Wd[i] = __float2bfloat16(wd[i]);
    }
  } else {
    const int wv_ = threadIdx.x >> 6, lane = threadIdx.x & 63;
    const int token = (blockIdx.x - 4096) * 4 + wv_;
    const float4 xv = ((const float4*)x)[token * 64 + lane];
    float ss = xv.x * xv.x + xv.y * xv.y + xv.z * xv.z + xv.w * xv.w;
#pragma unroll
    for (int off = 1; off < 64; off <<= 1) ss += __shfl_xor(ss, off, 64);
    const float inv = rsqrtf(ss * (1.0f / 256.0f) + 1e-5f);
    const float4 w4 = ((const float4*)rmsw)[lane];
    union { unsigned short u[4]; uint2 v2; } pk;
    bf16 b0 = __float2bfloat16(xv.x * inv * w4.x);
    bf16 b1 = __float2bfloat16(xv.y * inv * w4.y);
    bf16 b2 = __float2bfloat16(xv.z * inv * w4.z);
    bf16 b3 = __float2bfloat16(xv.w * inv * w4.w);
    pk.u[0] = *(unsigned short*)&b0; pk.u[1] = *(unsigned short*)&b1;
    pk.u[2] = *(unsigned short*)&b2; pk.u[3] = *(unsigned short*)&b3;
    ((uint2*)hb)[token * 64 + lane] = pk.v2;
  }
}

// ---------------- RMSNorm (1 wave per token) ----------------
__global__ void __launch_bounds__(256) rmsnorm_kernel(
    const float* __restrict__ x, const float* __restrict__ w, bf16* __restrict__ out) {
  const int wv = threadIdx.x >> 6, lane = threadIdx.x & 63;
  const int token = blockIdx.x * 4 + wv;
  const float4 xv = ((const float4*)x)[token * 64 + lane];
  float ss = xv.x * xv.x + xv.y * xv.y + xv.z * xv.z + xv.w * xv.w;
#pragma unroll
  for (int off = 1; off < 64; off <<= 1) ss += __shfl_xor(ss, off, 64);
  const float inv = rsqrtf(ss * (1.0f / 256.0f) + 1e-5f);
  const float4 w4 = ((const float4*)w)[lane];
  union { unsigned short u[4]; uint2 v2; } pk;
  bf16 b0 = __float2bfloat16(xv.x * inv * w4.x);
  bf16 b1 = __float2bfloat16(xv.y * inv * w4.y);
  bf16 b2 = __float2bfloat16(xv.z * inv * w4.z);
  bf16 b3 = __float2bfloat16(xv.w * inv * w4.w);
  pk.u[0] = *(unsigned short*)&b0; pk.u[1] = *(unsigned short*)&b1;
  pk.u[2] = *(unsigned short*)&b2; pk.u[3] = *(unsigned short*)&b3;
  ((uint2*)out)[token * 64 + lane] = pk.v2;
}

// ---------------- chunked-staging GEMM K-loop, bank-swizzled ----------------
// Stages KC/32 sub-tiles [16rows][32] per operand with one barrier pair per KC
// chunk. Bank swizzle: physical 16B col-group of row r holding global k-chunk g
// is (g + (r>>1)) & 3 -- chosen on the GLOBAL side of global_load_lds (LDS lane
// mapping is HW-fixed). Reader phase then spreads over all 8 bank-groups,
// 2 lanes each -> conflict-free (2-way is free, m136).
template <int BM, int BN, int KC>
static __device__ __forceinline__ void gemm_chunks(
    const bf16* __restrict__ Ag, const bf16* __restrict__ Bg,
    int lda, int ldb, int ktot,
    bf16* ldsA, bf16* ldsB, int wave, int lane,
    f32x4 (&acc)[BM / 32][BN / 32]) {
  const int lo = lane & 15, hi = lane >> 4;
  const int wm = (wave >> 1) * (BM / 2), wn = (wave & 1) * (BN / 2);
  const int lrow = lane >> 2;
  const int lcol = (((lane & 3) - (lane >> 3)) & 3) * 8;  // swizzled src k-group
  const int pcol = ((hi + (lo >> 1)) & 3) * 8;            // swizzled read col
  for (int kc = 0; kc < ktot; kc += KC) {
    __syncthreads();  // protect LDS reuse
#pragma unroll
    for (int c = 0; c < KC / 32; c++) {
      for (int is = wave; is < BM / 16; is += 4)
        gll16(Ag + (size_t)(is * 16 + lrow) * lda + kc + c * 32 + lcol,
              ldsA + c * (BM * 32) + is * 512);
      for (int is = wave; is < BN / 16; is += 4)
        gll16(Bg + (size_t)(is * 16 + lrow) * ldb + kc + c * 32 + lcol,
              ldsB + c * (BN * 32) + is * 512);
    }
    __syncthreads();  // staging complete (vmcnt drain once per chunk)
#pragma unroll
    for (int c = 0; c < KC / 32; c++) {
      bf16x8 af[BM / 32], bfr[BN / 32];
#pragma unroll
      for (int i = 0; i < BM / 32; i++)
        af[i] = ldb8(ldsA + c * (BM * 32) + (wm + i * 16 + lo) * 32 + pcol);
#pragma unroll
      for (int j = 0; j < BN / 32; j++)
        bfr[j] = ldb8(ldsB + c * (BN * 32) + (wn + j * 16 + lo) * 32 + pcol);
#pragma unroll
      for (int i = 0; i < BM / 32; i++)
#pragma unroll
        for (int j = 0; j < BN / 32; j++)
          acc[i][j] = mfma16(af[i], bfr[j], acc[i][j]);
    }
  }
}

// ---------------- QKV GEMM: 128x64 tiles, KC=128, grid (64, 12) ----------------
__global__ void __launch_bounds__(256) qkv_gemm(
    const bf16* __restrict__ A, const bf16* __restrict__ W,
    bf16* __restrict__ qb, bf16* __restrict__ kb, bf16* __restrict__ vtb) {
  __shared__ __align__(16) bf16 ldsA[128 * 128], ldsB[64 * 128];
  const int wave = threadIdx.x >> 6, lane = threadIdx.x & 63;
  const int lo = lane & 15, hi = lane >> 4;
  const int wm = (wave >> 1) * 64, wn = (wave & 1) * 32;
  f32x4 acc[4][2];
#pragma unroll
  for (int i = 0; i < 4; i++)
#pragma unroll
    for (int j = 0; j < 2; j++) acc[i][j] = (f32x4){0.f, 0.f, 0.f, 0.f};
  gemm_chunks<128, 64, 128>(A + (size_t)blockIdx.x * 128 * 256,
                            W + (size_t)blockIdx.y * 64 * 256,
                            256, 256, 256, ldsA, ldsB, wave, lane, acc);
#pragma unroll
  for (int i = 0; i < 4; i++)
#pragma unroll
    for (int j = 0; j < 2; j++) {
      const int o = blockIdx.y * 64 + wn + j * 16 + lo;
      const int sel = o >> 8, hd = (o >> 6) & 3, d = o & 63;
#pragma unroll
      for (int r = 0; r < 4; r++) {
        const int m = blockIdx.x * 128 + wm + i * 16 + hi * 4 + r;
        const int b = m >> 11, t = m & (TT - 1);
        const int bh = b * 4 + hd;
        const float v = acc[i][j][r];
        if (sel == 0)      qb[((size_t)bh * TT + t) * 64 + d] = __float2bfloat16(v * 0.125f);
        else if (sel == 1) kb[((size_t)bh * TT + t) * 64 + d] = __float2bfloat16(v);
        else               vtb[((size_t)bh * 64 + d) * TT + t] = __float2bfloat16(v);
      }
    }
}

// ---------------- flash attention v4: one qt per block, grid (64,16) --------
// Swapped-operand MFMA (A=K, B=Q -> S^T), packed b64 LDS P-writes, no-max
// softmax (scores bounded ~12.5). Longest q-tiles dispatched first; 1024
// blocks -> 4 blocks/CU for latency hiding.
__global__ void __launch_bounds__(256) attn_kernel(
    const bf16* __restrict__ qbp, const bf16* __restrict__ kbp,
    const bf16* __restrict__ vtp, bf16* __restrict__ aout) {
  const int wave = threadIdx.x >> 6, lane = threadIdx.x & 63;
  const int lo = lane & 15, hi = lane >> 4;
  const int bh = blockIdx.y;
  __shared__ __align__(16) unsigned short ldsP[4][2][16][40];  // P^T per wave/mf
  __shared__ __align__(16) unsigned short ldsO[4][32][88];     // bf16 partial O
  __shared__ float ldsL[4][2][16];
  const bf16* Q  = qbp + (size_t)bh * (TT * 64);
  const bf16* Kp = kbp + (size_t)bh * (TT * 64);
  const bf16* Vt = vtp + (size_t)bh * (64 * TT);
  const int b = bh >> 2, hd = bh & 3;

  const int qt = 63 - (int)blockIdx.x;  // longest q-tiles first
  const int q0 = qt * 32;
  const int ns = qt + 1;
  bf16x8 aq[2][2];
#pragma unroll
  for (int mf = 0; mf < 2; mf++)
#pragma unroll
    for (int h = 0; h < 2; h++)
      aq[mf][h] = ldb8(Q + (q0 + mf * 16 + lo) * 64 + h * 32 + hi * 8);
  f32x4 acc[2][4];
#pragma unroll
  for (int mf = 0; mf < 2; mf++)
#pragma unroll
    for (int dt = 0; dt < 4; dt++) acc[mf][dt] = (f32x4){0.f, 0.f, 0.f, 0.f};
  float lsum[2] = {0.f, 0.f};

  int i = wave;
  bf16x8 kf[2][2];
  if (i < ns) {
#pragma unroll
    for (int ct = 0; ct < 2; ct++) {
      const bf16* kr = Kp + (i * 32 + ct * 16 + lo) * 64 + hi * 8;
      kf[ct][0] = ldb8(kr);
      kf[ct][1] = ldb8(kr + 32);
    }
  }
  for (; i < ns; i += 4) {
    const int kt0 = i * 32;
    // QK^T swapped: S^T[kt][q]; lane: q = q0+mf*16+lo, kt = kt0+ct*16+hi*4+r
    f32x4 s[2][2];
#pragma unroll
    for (int mf = 0; mf < 2; mf++)
#pragma unroll
      for (int ct = 0; ct < 2; ct++) {
        f32x4 sc = (f32x4){0.f, 0.f, 0.f, 0.f};
        sc = mfma16(kf[ct][0], aq[mf][0], sc);
        sc = mfma16(kf[ct][1], aq[mf][1], sc);
        s[mf][ct] = sc;
      }
    // prefetch this wave's next K step (clamped re-load on last iter)
    const int ktn = (i + 4 < ns ? i + 4 : i) * 32;
    bf16x8 kn[2][2];
#pragma unroll
    for (int ct = 0; ct < 2; ct++) {
      const bf16* kr = Kp + (ktn + ct * 16 + lo) * 64 + hi * 8;
      kn[ct][0] = ldb8(kr);
      kn[ct][1] = ldb8(kr + 32);
    }
    // V loads for this step, issued ahead of the exp section
    bf16x8 vb[4];
#pragma unroll
    for (int dt = 0; dt < 4; dt++)
      vb[dt] = ldb8(Vt + (dt * 16 + lo) * TT + kt0 + hi * 8);
    if (i == ns - 1) {  // diagonal step: causal mask
#pragma unroll
      for (int mf = 0; mf < 2; mf++)
#pragma unroll
        for (int ct = 0; ct < 2; ct++)
#pragma unroll
          for (int r = 0; r < 4; r++)
            if (kt0 + ct * 16 + hi * 4 + r > q0 + mf * 16 + lo) s[mf][ct][r] = -INFINITY;
    }
#pragma unroll
    for (int mf = 0; mf < 2; mf++)
#pragma unroll
      for (int ct = 0; ct < 2; ct++) {
        union { unsigned short u[4]; uint2 v2; } pk;
#pragma unroll
        for (int r = 0; r < 4; r++) {
          const float p = __expf(s[mf][ct][r]);  // exp(-inf)=0 handles mask
          lsum[mf] += p;
          bf16 pb = __float2bfloat16(p);
          pk.u[r] = *(unsigned short*)&pb;
        }
        *(uint2*)&ldsP[wave][mf][lo][ct * 16 + hi * 4] = pk.v2;
      }
    // intra-wave LDS write->read ordering only (waves independent here)
    asm volatile("s_waitcnt lgkmcnt(0)" ::: "memory");
    bf16x8 pa[2];
#pragma unroll
    for (int mf = 0; mf < 2; mf++)
      pa[mf] = *(const bf16x8*)&ldsP[wave][mf][lo][hi * 8];
    // O^T = V^T x P^T: lane: d = dt*16+hi*4+r, q = q0+mf*16+lo
#pragma unroll
    for (int mf = 0; mf < 2; mf++)
#pragma unroll
      for (int dt = 0; dt < 4; dt++)
        acc[mf][dt] = mfma16(vb[dt], pa[mf], acc[mf][dt]);
#pragma unroll
    for (int ct = 0; ct < 2; ct++) {
      kf[ct][0] = kn[ct][0];
      kf[ct][1] = kn[ct][1];
    }
  }

  // reduce lsum across the 4 hi replicas (lanes lo, lo+16, lo+32, lo+48)
#pragma unroll
  for (int mf = 0; mf < 2; mf++) {
    lsum[mf] += __shfl_xor(lsum[mf], 16, 64);
    lsum[mf] += __shfl_xor(lsum[mf], 32, 64);
  }
  if (hi == 0) {
    ldsL[wave][0][lo] = lsum[0];
    ldsL[wave][1][lo] = lsum[1];
  }
  // publish bf16 partial O^T: lane packs 4 consecutive d for its q
#pragma unroll
  for (int mf = 0; mf < 2; mf++)
#pragma unroll
    for (int dt = 0; dt < 4; dt++) {
      union { unsigned short u[4]; uint2 v2; } pk;
#pragma unroll
      for (int r = 0; r < 4; r++) {
        bf16 ob = __float2bfloat16(acc[mf][dt][r]);
        pk.u[r] = *(unsigned short*)&ob;
      }
      *(uint2*)&ldsO[wave][mf * 16 + lo][dt * 16 + hi * 4] = pk.v2;
    }
  __syncthreads();

  // combine: thread t owns q row t>>3, d-slice ((t&7)*8 .. +7)
  const int q = threadIdx.x >> 3;
  const int d0 = (threadIdx.x & 7) * 8;
  const float L = ldsL[0][q >> 4][q & 15] + ldsL[1][q >> 4][q & 15] +
                  ldsL[2][q >> 4][q & 15] + ldsL[3][q >> 4][q & 15];
  float o[8] = {0.f, 0.f, 0.f, 0.f, 0.f, 0.f, 0.f, 0.f};
#pragma unroll
  for (int w = 0; w < 4; w++) {
    const bf16x8 v = *(const bf16x8*)&ldsO[w][q][d0];
#pragma unroll
    for (int j = 0; j < 8; j++) o[j] += (float)v[j];
  }
  const float invL = 1.0f / L;
  bf16* dst = aout + ((size_t)(b * TT + q0 + q)) * 256 + hd * 64 + d0;
  union { unsigned short u[8]; uint4 v4; } pk;
#pragma unroll
  for (int j = 0; j < 8; j++) {
    bf16 ob = __float2bfloat16(o[j] * invL);
    pk.u[j] = *(unsigned short*)&ob;
  }
  *(uint4*)dst = pk.v4;
}

// ---------------- WO GEMM + residual: 64x64, KC=256, grid (128,4) ----------------
__global__ void __launch_bounds__(256) wo_gemm(
    const bf16* __restrict__ A, const bf16* __restrict__ W,
    const float* __restrict__ x, float* __restrict__ x2) {
  __shared__ __align__(16) bf16 ldsA[64 * 256], ldsB[64 * 256];
  const int wave = threadIdx.x >> 6, lane = threadIdx.x & 63;
  const int lo = lane & 15, hi = lane >> 4;
  const int wm = (wave >> 1) * 32, wn = (wave & 1) * 32;
  f32x4 acc[2][2];
#pragma unroll
  for (int i = 0; i < 2; i++)
#pragma unroll
    for (int j = 0; j < 2; j++) acc[i][j] = (f32x4){0.f, 0.f, 0.f, 0.f};
  gemm_chunks<64, 64, 256>(A + (size_t)blockIdx.x * 64 * 256,
                           W + (size_t)blockIdx.y * 64 * 256,
                           256, 256, 256, ldsA, ldsB, wave, lane, acc);
#pragma unroll
  for (int i = 0; i < 2; i++)
#pragma unroll
    for (int j = 0; j < 2; j++) {
      const int col = blockIdx.y * 64 + wn + j * 16 + lo;
#pragma unroll
      for (int r = 0; r < 4; r++) {
        const size_t idx = (size_t)(blockIdx.x * 64 + wm + i * 16 + hi * 4 + r) * 256 + col;
        x2[idx] = x[idx] + acc[i][j][r];
      }
    }
}

// ---------------- gate/up GEMM + SiLU: 128x128, KC=128, grid (64, 16) ----------------
__global__ void __launch_bounds__(256) gu_gemm(
    const bf16* __restrict__ A, const bf16* __restrict__ W, bf16* __restrict__ mid) {
  __shared__ __align__(16) bf16 ldsA[128 * 128], ldsB[128 * 128];
  const int wave = threadIdx.x >> 6, lane = threadIdx.x & 63;
  const int lo = lane & 15, hi = lane >> 4;
  const int wm = (wave >> 1) * 64, wn = (wave & 1) * 64;
  f32x4 acc[4][4];
#pragma unroll
  for (int i = 0; i < 4; i++)
#pragma unroll
    for (int j = 0; j < 4; j++) acc[i][j] = (f32x4){0.f, 0.f, 0.f, 0.f};
  gemm_chunks<128, 128, 128>(A + (size_t)blockIdx.x * 128 * 256,
                             W + (size_t)blockIdx.y * 128 * 256,
                             256, 256, 256, ldsA, ldsB, wave, lane, acc);
#pragma unroll
  for (int i = 0; i < 4; i++)
#pragma unroll
    for (int jp = 0; jp < 2; jp++) {
      const int f = (blockIdx.y * 4 + (wn >> 5) + jp) * 16 + lo;
#pragma unroll
      for (int r = 0; r < 4; r++) {
        const int m = blockIdx.x * 128 + wm + i * 16 + hi * 4 + r;
        const float g = acc[i][2 * jp][r];
        const float u = acc[i][2 * jp + 1][r];
        const float sv = g / (1.f + __expf(-g)) * u;
        mid[(size_t)m * 1024 + f] = __float2bfloat16(sv);
      }
    }
}

// ---------------- down GEMM + residual: 64x64, KC=256, grid (128,4) ------
__global__ void __launch_bounds__(256) down_gemm(
    const bf16* __restrict__ A, const bf16* __restrict__ W,
    const float* __restrict__ x2, float* __restrict__ out) {
  __shared__ __align__(16) bf16 ldsA[64 * 256], ldsB[64 * 256];
  const int wave = threadIdx.x >> 6, lane = threadIdx.x & 63;
  const int lo = lane & 15, hi = lane >> 4;
  const int wm = (wave >> 1) * 32, wn = (wave & 1) * 32;
  f32x4 acc[2][2];
#pragma unroll
  for (int i = 0; i < 2; i++)
#pragma unroll
    for (int j = 0; j < 2; j++) acc[i][j] = (f32x4){0.f, 0.f, 0.f, 0.f};
  gemm_chunks<64, 64, 256>(A + (size_t)blockIdx.x * 64 * 1024,
                           W + (size_t)blockIdx.y * 64 * 1024,
                           1024, 1024, 1024, ldsA, ldsB, wave, lane, acc);
#pragma unroll
  for (int i = 0; i < 2; i++)
#pragma unroll
    for (int j = 0; j < 2; j++) {
      const int col = blockIdx.y * 64 + wn + j * 16 + lo;
#pragma unroll
      for (int r = 0; r < 4; r++) {
        const size_t idx = (size_t)(blockIdx.x * 64 + wm + i * 16 + hi * 4 + r) * 256 + col;
        out[idx] = x2[idx] + acc[i][j][r];
      }
    }
}

extern "C" void kernel_launch(void* const* d_in, const int* in_sizes, int n_in,
                              void* d_out, int out_size, void* d_ws, size_t ws_size,
                              hipStream_t stream) {
  const float* x          = (const float*)d_in[0];
  const float* rms_attn_w = (const float*)d_in[2];
  const float* wq         = (const float*)d_in[3];
  const float* wk         = (const float*)d_in[4];
  const float* wv         = (const float*)d_in[5];
  const float* wo         = (const float*)d_in[6];
  const float* rms_ffn_w  = (const float*)d_in[7];
  const float* wg         = (const float*)d_in[8];
  const float* wu         = (const float*)d_in[9];
  const float* wd         = (const float*)d_in[10];
  float* out = (float*)d_out;
  char* ws = (char*)d_ws;

  bf16* Wqkv  = (bf16*)(ws + 0);
  bf16* Wo    = (bf16*)(ws + 393216);
  bf16* Wgu   = (bf16*)(ws + 524288);
  bf16* Wd    = (bf16*)(ws + 1572864);
  bf16* hb    = (bf16*)(ws + 2097152);
  bf16* qb    = (bf16*)(ws + 6291456);
  bf16* kb    = (bf16*)(ws + 10485760);
  bf16* vtb   = (bf16*)(ws + 14680064);
  bf16* attnb = (bf16*)(ws + 18874368);
  float* x2   = (float*)(ws + 23068672);
  bf16* h2b   = (bf16*)(ws + 31457280);
  bf16* midb  = (bf16*)(ws + 35651584);

  hipLaunchKernelGGL(prep_kernel, dim3(6144), dim3(256), 0, stream,
                     wq, wk, wv, wo, wg, wu, wd, Wqkv, Wo, Wgu, Wd,
                     x, rms_attn_w, hb);
  hipLaunchKernelGGL(qkv_gemm, dim3(64, 12), dim3(256), 0, stream, hb, Wqkv, qb, kb, vtb);
  hipLaunchKernelGGL(attn_kernel, dim3(64, 16), dim3(256), 0, stream, qb, kb, vtb, attnb);
  hipLaunchKernelGGL(wo_gemm, dim3(128, 4), dim3(256), 0, stream, attnb, Wo, x, x2);
  hipLaunchKernelGGL(rmsnorm_kernel, dim3(2048), dim3(256), 0, stream, x2, rms_ffn_w, h2b);
  hipLaunchKernelGGL(gu_gemm, dim3(64, 16), dim3(256), 0, stream, h2b, Wgu, midb);
  hipLaunchKernelGGL(down_gemm, dim3(128, 4), dim3(256), 0, stream, midb, Wd, x2, out);
}

// Round 8
// 166.466 us; speedup vs baseline: 1.1512x; 1.1512x over previous
//
#include <hip/hip_runtime.h>
#include <hip/hip_bf16.h>
#include <math.h>

#define TT 2048
typedef __bf16 bf16x8 __attribute__((ext_vector_type(8)));
typedef float f32x4 __attribute__((ext_vector_type(4)));
typedef __hip_bfloat16 bf16;

static __device__ __forceinline__ f32x4 mfma16(bf16x8 a, bf16x8 b, f32x4 c) {
  return __builtin_amdgcn_mfma_f32_16x16x32_bf16(a, b, c, 0, 0, 0);
}
static __device__ __forceinline__ bf16x8 ldb8(const bf16* p) {
  return *(const bf16x8*)p;
}
// async global->LDS, 16B per lane; lds base must be wave-uniform (HW adds lane*16)
static __device__ __forceinline__ void gll16(const bf16* g, bf16* l) {
  __builtin_amdgcn_global_load_lds(
      (const __attribute__((address_space(1))) unsigned int*)g,
      (__attribute__((address_space(3))) unsigned int*)l, 16, 0, 0);
}

// ---------------- fused weight convert/pack + attn RMSNorm ----------------
__global__ void __launch_bounds__(256) prep_kernel(
    const float* __restrict__ wq, const float* __restrict__ wk,
    const float* __restrict__ wv, const float* __restrict__ wo,
    const float* __restrict__ wg, const float* __restrict__ wu,
    const float* __restrict__ wd,
    bf16* __restrict__ Wqkv, bf16* __restrict__ Wo,
    bf16* __restrict__ Wgu, bf16* __restrict__ Wd,
    const float* __restrict__ x, const float* __restrict__ rmsw,
    bf16* __restrict__ hb) {
  if (blockIdx.x < 4096) {
    int idx = blockIdx.x * 256 + threadIdx.x;  // 0 .. 1048575
    if (idx < 196608) {                        // QKV pack
      int row = idx >> 8, col = idx & 255;
      const float* src = row < 256 ? wq : (row < 512 ? wk : wv);
      Wqkv[idx] = __float2bfloat16(src[(row & 255) * 256 + col]);
    } else if (idx < 262144) {
      int i = idx - 196608;
      Wo[i] = __float2bfloat16(wo[i]);
    } else if (idx < 786432) {                 // gate/up interleaved per 16 rows
      int i = idx - 262144;
      int row = i >> 8, col = i & 255;
      int t = row >> 4, r = row & 15;
      int f = (t >> 1) * 16 + r;
      const float* src = (t & 1) ? wu : wg;
      Wgu[i] = __float2bfloat16(src[f * 256 + col]);
    } else {
      int i = idx - 786432;
      Wd[i] = __float2bfloat16(wd[i]);
    }
  } else {
    const int wv_ = threadIdx.x >> 6, lane = threadIdx.x & 63;
    const int token = (blockIdx.x - 4096) * 4 + wv_;
    const float4 xv = ((const float4*)x)[token * 64 + lane];
    float ss = xv.x * xv.x + xv.y * xv.y + xv.z * xv.z + xv.w * xv.w;
#pragma unroll
    for (int off = 1; off < 64; off <<= 1) ss += __shfl_xor(ss, off, 64);
    const float inv = rsqrtf(ss * (1.0f / 256.0f) + 1e-5f);
    const float4 w4 = ((const float4*)rmsw)[lane];
    union { unsigned short u[4]; uint2 v2; } pk;
    bf16 b0 = __float2bfloat16(xv.x * inv * w4.x);
    bf16 b1 = __float2bfloat16(xv.y * inv * w4.y);
    bf16 b2 = __float2bfloat16(xv.z * inv * w4.z);
    bf16 b3 = __float2bfloat16(xv.w * inv * w4.w);
    pk.u[0] = *(unsigned short*)&b0; pk.u[1] = *(unsigned short*)&b1;
    pk.u[2] = *(unsigned short*)&b2; pk.u[3] = *(unsigned short*)&b3;
    ((uint2*)hb)[token * 64 + lane] = pk.v2;
  }
}

// ---------------- RMSNorm (1 wave per token) ----------------
__global__ void __launch_bounds__(256) rmsnorm_kernel(
    const float* __restrict__ x, const float* __restrict__ w, bf16* __restrict__ out) {
  const int wv = threadIdx.x >> 6, lane = threadIdx.x & 63;
  const int token = blockIdx.x * 4 + wv;
  const float4 xv = ((const float4*)x)[token * 64 + lane];
  float ss = xv.x * xv.x + xv.y * xv.y + xv.z * xv.z + xv.w * xv.w;
#pragma unroll
  for (int off = 1; off < 64; off <<= 1) ss += __shfl_xor(ss, off, 64);
  const float inv = rsqrtf(ss * (1.0f / 256.0f) + 1e-5f);
  const float4 w4 = ((const float4*)w)[lane];
  union { unsigned short u[4]; uint2 v2; } pk;
  bf16 b0 = __float2bfloat16(xv.x * inv * w4.x);
  bf16 b1 = __float2bfloat16(xv.y * inv * w4.y);
  bf16 b2 = __float2bfloat16(xv.z * inv * w4.z);
  bf16 b3 = __float2bfloat16(xv.w * inv * w4.w);
  pk.u[0] = *(unsigned short*)&b0; pk.u[1] = *(unsigned short*)&b1;
  pk.u[2] = *(unsigned short*)&b2; pk.u[3] = *(unsigned short*)&b3;
  ((uint2*)out)[token * 64 + lane] = pk.v2;
}

// ---------------- chunked-staging GEMM K-loop ----------------
// Stages KC/32 sub-tiles [rows][32] (m97 bank pattern, gll16 lane mapping)
// in ONE barrier pair per KC chunk, then runs KC/32 barrier-free MFMA steps.
template <int BM, int BN, int KC>
static __device__ __forceinline__ void gemm_chunks(
    const bf16* __restrict__ Ag, const bf16* __restrict__ Bg,
    int lda, int ldb, int ktot,
    bf16* ldsA, bf16* ldsB, int wave, int lane,
    f32x4 (&acc)[BM / 32][BN / 32]) {
  const int lo = lane & 15, hi = lane >> 4;
  const int wm = (wave >> 1) * (BM / 2), wn = (wave & 1) * (BN / 2);
  const int lrow = lane >> 2, lcol = (lane & 3) * 8;
  for (int kc = 0; kc < ktot; kc += KC) {
    __syncthreads();  // protect LDS reuse
#pragma unroll
    for (int c = 0; c < KC / 32; c++) {
      for (int is = wave; is < BM / 16; is += 4)
        gll16(Ag + (size_t)(is * 16 + lrow) * lda + kc + c * 32 + lcol,
              ldsA + c * (BM * 32) + is * 512);
      for (int is = wave; is < BN / 16; is += 4)
        gll16(Bg + (size_t)(is * 16 + lrow) * ldb + kc + c * 32 + lcol,
              ldsB + c * (BN * 32) + is * 512);
    }
    __syncthreads();  // staging complete (vmcnt drain once per chunk)
#pragma unroll
    for (int c = 0; c < KC / 32; c++) {
      bf16x8 af[BM / 32], bfr[BN / 32];
#pragma unroll
      for (int i = 0; i < BM / 32; i++)
        af[i] = ldb8(ldsA + c * (BM * 32) + (wm + i * 16 + lo) * 32 + hi * 8);
#pragma unroll
      for (int j = 0; j < BN / 32; j++)
        bfr[j] = ldb8(ldsB + c * (BN * 32) + (wn + j * 16 + lo) * 32 + hi * 8);
#pragma unroll
      for (int i = 0; i < BM / 32; i++)
#pragma unroll
        for (int j = 0; j < BN / 32; j++)
          acc[i][j] = mfma16(af[i], bfr[j], acc[i][j]);
    }
  }
}

// ---------------- QKV GEMM: 128x64 tiles, KC=128, grid (64, 12) ----------------
// V^T written kt-tiled: [bh][kt>>5][d][kt&31] so attention PV loads are
// contiguous 4KB tiles.
__global__ void __launch_bounds__(256) qkv_gemm(
    const bf16* __restrict__ A, const bf16* __restrict__ W,
    bf16* __restrict__ qb, bf16* __restrict__ kb, bf16* __restrict__ vtb) {
  __shared__ __align__(16) bf16 ldsA[128 * 128], ldsB[64 * 128];
  const int wave = threadIdx.x >> 6, lane = threadIdx.x & 63;
  const int lo = lane & 15, hi = lane >> 4;
  const int wm = (wave >> 1) * 64, wn = (wave & 1) * 32;
  f32x4 acc[4][2];
#pragma unroll
  for (int i = 0; i < 4; i++)
#pragma unroll
    for (int j = 0; j < 2; j++) acc[i][j] = (f32x4){0.f, 0.f, 0.f, 0.f};
  gemm_chunks<128, 64, 128>(A + (size_t)blockIdx.x * 128 * 256,
                            W + (size_t)blockIdx.y * 64 * 256,
                            256, 256, 256, ldsA, ldsB, wave, lane, acc);
#pragma unroll
  for (int i = 0; i < 4; i++)
#pragma unroll
    for (int j = 0; j < 2; j++) {
      const int o = blockIdx.y * 64 + wn + j * 16 + lo;
      const int sel = o >> 8, hd = (o >> 6) & 3, d = o & 63;
#pragma unroll
      for (int r = 0; r < 4; r++) {
        const int m = blockIdx.x * 128 + wm + i * 16 + hi * 4 + r;
        const int b = m >> 11, t = m & (TT - 1);
        const int bh = b * 4 + hd;
        const float v = acc[i][j][r];
        if (sel == 0)      qb[((size_t)bh * TT + t) * 64 + d] = __float2bfloat16(v * 0.125f);
        else if (sel == 1) kb[((size_t)bh * TT + t) * 64 + d] = __float2bfloat16(v);
        else               vtb[(size_t)bh * (64 * TT) + (t >> 5) * 2048 + d * 32 + (t & 31)]
                               = __float2bfloat16(v);
      }
    }
}

// ---------------- flash attention v5: paired qt, kt-tiled V^T ----------------
// Swapped-operand MFMA (A=K, B=Q -> S^T), packed b64 LDS P-writes, no-max
// softmax (scores bounded ~12.5). qt-pairing: block does tiles qtp and
// 63-qtp => all 512 blocks do exactly 65 steps (uniform per-CU work under
// full co-residency). V^T kt-tiled: each 64x32 PV tile contiguous (coalesced).
__global__ void __launch_bounds__(256) attn_kernel(
    const bf16* __restrict__ qbp, const bf16* __restrict__ kbp,
    const bf16* __restrict__ vtp, bf16* __restrict__ aout) {
  const int wave = threadIdx.x >> 6, lane = threadIdx.x & 63;
  const int lo = lane & 15, hi = lane >> 4;
  const int bh = blockIdx.y;
  __shared__ __align__(16) unsigned short ldsP[4][2][16][40];  // P^T per wave/mf
  __shared__ __align__(16) unsigned short ldsO[4][32][88];     // bf16 partial O
  __shared__ float ldsL[4][2][16];
  const bf16* Q  = qbp + (size_t)bh * (TT * 64);
  const bf16* Kp = kbp + (size_t)bh * (TT * 64);
  const bf16* Vt = vtp + (size_t)bh * (64 * TT);
  const int b = bh >> 2, hd = bh & 3;

  for (int half = 0; half < 2; half++) {
    const int qt = half == 0 ? (int)blockIdx.x : 63 - (int)blockIdx.x;
    const int q0 = qt * 32;
    const int ns = qt + 1;
    bf16x8 aq[2][2];
#pragma unroll
    for (int mf = 0; mf < 2; mf++)
#pragma unroll
      for (int h = 0; h < 2; h++)
        aq[mf][h] = ldb8(Q + (q0 + mf * 16 + lo) * 64 + h * 32 + hi * 8);
    f32x4 acc[2][4];
#pragma unroll
    for (int mf = 0; mf < 2; mf++)
#pragma unroll
      for (int dt = 0; dt < 4; dt++) acc[mf][dt] = (f32x4){0.f, 0.f, 0.f, 0.f};
    float lsum[2] = {0.f, 0.f};

    int i = wave;
    bf16x8 kf[2][2];
    if (i < ns) {
#pragma unroll
      for (int ct = 0; ct < 2; ct++) {
        const bf16* kr = Kp + (i * 32 + ct * 16 + lo) * 64 + hi * 8;
        kf[ct][0] = ldb8(kr);
        kf[ct][1] = ldb8(kr + 32);
      }
    }
    for (; i < ns; i += 4) {
      const int kt0 = i * 32;
      // QK^T swapped: S^T[kt][q]; lane: q = q0+mf*16+lo, kt = kt0+ct*16+hi*4+r
      f32x4 s[2][2];
#pragma unroll
      for (int mf = 0; mf < 2; mf++)
#pragma unroll
        for (int ct = 0; ct < 2; ct++) {
          f32x4 sc = (f32x4){0.f, 0.f, 0.f, 0.f};
          sc = mfma16(kf[ct][0], aq[mf][0], sc);
          sc = mfma16(kf[ct][1], aq[mf][1], sc);
          s[mf][ct] = sc;
        }
      // prefetch this wave's next K step (clamped re-load on last iter)
      const int ktn = (i + 4 < ns ? i + 4 : i) * 32;
      bf16x8 kn[2][2];
#pragma unroll
      for (int ct = 0; ct < 2; ct++) {
        const bf16* kr = Kp + (ktn + ct * 16 + lo) * 64 + hi * 8;
        kn[ct][0] = ldb8(kr);
        kn[ct][1] = ldb8(kr + 32);
      }
      // V loads (kt-tiled: contiguous 4KB tile), ahead of the exp section
      const bf16* vtile = Vt + i * 2048;
      bf16x8 vb[4];
#pragma unroll
      for (int dt = 0; dt < 4; dt++)
        vb[dt] = ldb8(vtile + (dt * 16 + lo) * 32 + hi * 8);
      if (i == ns - 1) {  // diagonal step: causal mask
#pragma unroll
        for (int mf = 0; mf < 2; mf++)
#pragma unroll
          for (int ct = 0; ct < 2; ct++)
#pragma unroll
            for (int r = 0; r < 4; r++)
              if (kt0 + ct * 16 + hi * 4 + r > q0 + mf * 16 + lo) s[mf][ct][r] = -INFINITY;
      }
#pragma unroll
      for (int mf = 0; mf < 2; mf++)
#pragma unroll
        for (int ct = 0; ct < 2; ct++) {
          union { unsigned short u[4]; uint2 v2; } pk;
#pragma unroll
          for (int r = 0; r < 4; r++) {
            const float p = __expf(s[mf][ct][r]);  // exp(-inf)=0 handles mask
            lsum[mf] += p;
            bf16 pb = __float2bfloat16(p);
            pk.u[r] = *(unsigned short*)&pb;
          }
          *(uint2*)&ldsP[wave][mf][lo][ct * 16 + hi * 4] = pk.v2;
        }
      // intra-wave LDS write->read ordering only (waves independent here)
      asm volatile("s_waitcnt lgkmcnt(0)" ::: "memory");
      bf16x8 pa[2];
#pragma unroll
      for (int mf = 0; mf < 2; mf++)
        pa[mf] = *(const bf16x8*)&ldsP[wave][mf][lo][hi * 8];
      // O^T = V^T x P^T: lane: d = dt*16+hi*4+r, q = q0+mf*16+lo
#pragma unroll
      for (int mf = 0; mf < 2; mf++)
#pragma unroll
        for (int dt = 0; dt < 4; dt++)
          acc[mf][dt] = mfma16(vb[dt], pa[mf], acc[mf][dt]);
#pragma unroll
      for (int ct = 0; ct < 2; ct++) {
        kf[ct][0] = kn[ct][0];
        kf[ct][1] = kn[ct][1];
      }
    }

    // reduce lsum across the 4 hi replicas
#pragma unroll
    for (int mf = 0; mf < 2; mf++) {
      lsum[mf] += __shfl_xor(lsum[mf], 16, 64);
      lsum[mf] += __shfl_xor(lsum[mf], 32, 64);
    }
    if (hi == 0) {
      ldsL[wave][0][lo] = lsum[0];
      ldsL[wave][1][lo] = lsum[1];
    }
    // publish bf16 partial O^T: lane packs 4 consecutive d for its q
#pragma unroll
    for (int mf = 0; mf < 2; mf++)
#pragma unroll
      for (int dt = 0; dt < 4; dt++) {
        union { unsigned short u[4]; uint2 v2; } pk;
#pragma unroll
        for (int r = 0; r < 4; r++) {
          bf16 ob = __float2bfloat16(acc[mf][dt][r]);
          pk.u[r] = *(unsigned short*)&ob;
        }
        *(uint2*)&ldsO[wave][mf * 16 + lo][dt * 16 + hi * 4] = pk.v2;
      }
    __syncthreads();

    // combine: thread t owns q row t>>3, d-slice ((t&7)*8 .. +7)
    const int q = threadIdx.x >> 3;
    const int d0 = (threadIdx.x & 7) * 8;
    const float L = ldsL[0][q >> 4][q & 15] + ldsL[1][q >> 4][q & 15] +
                    ldsL[2][q >> 4][q & 15] + ldsL[3][q >> 4][q & 15];
    float o[8] = {0.f, 0.f, 0.f, 0.f, 0.f, 0.f, 0.f, 0.f};
#pragma unroll
    for (int w = 0; w < 4; w++) {
      const bf16x8 v = *(const bf16x8*)&ldsO[w][q][d0];
#pragma unroll
      for (int j = 0; j < 8; j++) o[j] += (float)v[j];
    }
    const float invL = 1.0f / L;
    bf16* dst = aout + ((size_t)(b * TT + q0 + q)) * 256 + hd * 64 + d0;
    union { unsigned short u[8]; uint4 v4; } pk;
#pragma unroll
    for (int j = 0; j < 8; j++) {
      bf16 ob = __float2bfloat16(o[j] * invL);
      pk.u[j] = *(unsigned short*)&ob;
    }
    *(uint4*)dst = pk.v4;
    __syncthreads();  // ldsO/ldsL reused by next half
  }
}

// ---------------- WO GEMM + residual: 64x64, KC=256, grid (128,4) ----------------
__global__ void __launch_bounds__(256) wo_gemm(
    const bf16* __restrict__ A, const bf16* __restrict__ W,
    const float* __restrict__ x, float* __restrict__ x2) {
  __shared__ __align__(16) bf16 ldsA[64 * 256], ldsB[64 * 256];
  const int wave = threadIdx.x >> 6, lane = threadIdx.x & 63;
  const int lo = lane & 15, hi = lane >> 4;
  const int wm = (wave >> 1) * 32, wn = (wave & 1) * 32;
  f32x4 acc[2][2];
#pragma unroll
  for (int i = 0; i < 2; i++)
#pragma unroll
    for (int j = 0; j < 2; j++) acc[i][j] = (f32x4){0.f, 0.f, 0.f, 0.f};
  gemm_chunks<64, 64, 256>(A + (size_t)blockIdx.x * 64 * 256,
                           W + (size_t)blockIdx.y * 64 * 256,
                           256, 256, 256, ldsA, ldsB, wave, lane, acc);
#pragma unroll
  for (int i = 0; i < 2; i++)
#pragma unroll
    for (int j = 0; j < 2; j++) {
      const int col = blockIdx.y * 64 + wn + j * 16 + lo;
#pragma unroll
      for (int r = 0; r < 4; r++) {
        const size_t idx = (size_t)(blockIdx.x * 64 + wm + i * 16 + hi * 4 + r) * 256 + col;
        x2[idx] = x[idx] + acc[i][j][r];
      }
    }
}

// ---------------- gate/up GEMM + SiLU: 128x128, KC=128, grid (64, 16) ----------------
__global__ void __launch_bounds__(256) gu_gemm(
    const bf16* __restrict__ A, const bf16* __restrict__ W, bf16* __restrict__ mid) {
  __shared__ __align__(16) bf16 ldsA[128 * 128], ldsB[128 * 128];
  const int wave = threadIdx.x >> 6, lane = threadIdx.x & 63;
  const int lo = lane & 15, hi = lane >> 4;
  const int wm = (wave >> 1) * 64, wn = (wave & 1) * 64;
  f32x4 acc[4][4];
#pragma unroll
  for (int i = 0; i < 4; i++)
#pragma unroll
    for (int j = 0; j < 4; j++) acc[i][j] = (f32x4){0.f, 0.f, 0.f, 0.f};
  gemm_chunks<128, 128, 128>(A + (size_t)blockIdx.x * 128 * 256,
                             W + (size_t)blockIdx.y * 128 * 256,
                             256, 256, 256, ldsA, ldsB, wave, lane, acc);
#pragma unroll
  for (int i = 0; i < 4; i++)
#pragma unroll
    for (int jp = 0; jp < 2; jp++) {
      const int f = (blockIdx.y * 4 + (wn >> 5) + jp) * 16 + lo;
#pragma unroll
      for (int r = 0; r < 4; r++) {
        const int m = blockIdx.x * 128 + wm + i * 16 + hi * 4 + r;
        const float g = acc[i][2 * jp][r];
        const float u = acc[i][2 * jp + 1][r];
        const float sv = g / (1.f + __expf(-g)) * u;
        mid[(size_t)m * 1024 + f] = __float2bfloat16(sv);
      }
    }
}

// ---------------- down GEMM + residual: 64x64, KC=256, grid (128,4) ------
__global__ void __launch_bounds__(256) down_gemm(
    const bf16* __restrict__ A, const bf16* __restrict__ W,
    const float* __restrict__ x2, float* __restrict__ out) {
  __shared__ __align__(16) bf16 ldsA[64 * 256], ldsB[64 * 256];
  const int wave = threadIdx.x >> 6, lane = threadIdx.x & 63;
  const int lo = lane & 15, hi = lane >> 4;
  const int wm = (wave >> 1) * 32, wn = (wave & 1) * 32;
  f32x4 acc[2][2];
#pragma unroll
  for (int i = 0; i < 2; i++)
#pragma unroll
    for (int j = 0; j < 2; j++) acc[i][j] = (f32x4){0.f, 0.f, 0.f, 0.f};
  gemm_chunks<64, 64, 256>(A + (size_t)blockIdx.x * 64 * 1024,
                           W + (size_t)blockIdx.y * 64 * 1024,
                           1024, 1024, 1024, ldsA, ldsB, wave, lane, acc);
#pragma unroll
  for (int i = 0; i < 2; i++)
#pragma unroll
    for (int j = 0; j < 2; j++) {
      const int col = blockIdx.y * 64 + wn + j * 16 + lo;
#pragma unroll
      for (int r = 0; r < 4; r++) {
        const size_t idx = (size_t)(blockIdx.x * 64 + wm + i * 16 + hi * 4 + r) * 256 + col;
        out[idx] = x2[idx] + acc[i][j][r];
      }
    }
}

extern "C" void kernel_launch(void* const* d_in, const int* in_sizes, int n_in,
                              void* d_out, int out_size, void* d_ws, size_t ws_size,
                              hipStream_t stream) {
  const float* x          = (const float*)d_in[0];
  const float* rms_attn_w = (const float*)d_in[2];
  const float* wq         = (const float*)d_in[3];
  const float* wk         = (const float*)d_in[4];
  const float* wv         = (const float*)d_in[5];
  const float* wo         = (const float*)d_in[6];
  const float* rms_ffn_w  = (const float*)d_in[7];
  const float* wg         = (const float*)d_in[8];
  const float* wu         = (const float*)d_in[9];
  const float* wd         = (const float*)d_in[10];
  float* out = (float*)d_out;
  char* ws = (char*)d_ws;

  bf16* Wqkv  = (bf16*)(ws + 0);
  bf16* Wo    = (bf16*)(ws + 393216);
  bf16* Wgu   = (bf16*)(ws + 524288);
  bf16* Wd    = (bf16*)(ws + 1572864);
  bf16* hb    = (bf16*)(ws + 2097152);
  bf16* qb    = (bf16*)(ws + 6291456);
  bf16* kb    = (bf16*)(ws + 10485760);
  bf16* vtb   = (bf16*)(ws + 14680064);
  bf16* attnb = (bf16*)(ws + 18874368);
  float* x2   = (float*)(ws + 23068672);
  bf16* h2b   = (bf16*)(ws + 31457280);
  bf16* midb  = (bf16*)(ws + 35651584);

  hipLaunchKernelGGL(prep_kernel, dim3(6144), dim3(256), 0, stream,
                     wq, wk, wv, wo, wg, wu, wd, Wqkv, Wo, Wgu, Wd,
                     x, rms_attn_w, hb);
  hipLaunchKernelGGL(qkv_gemm, dim3(64, 12), dim3(256), 0, stream, hb, Wqkv, qb, kb, vtb);
  hipLaunchKernelGGL(attn_kernel, dim3(32, 16), dim3(256), 0, stream, qb, kb, vtb, attnb);
  hipLaunchKernelGGL(wo_gemm, dim3(128, 4), dim3(256), 0, stream, attnb, Wo, x, x2);
  hipLaunchKernelGGL(rmsnorm_kernel, dim3(2048), dim3(256), 0, stream, x2, rms_ffn_w, h2b);
  hipLaunchKernelGGL(gu_gemm, dim3(64, 16), dim3(256), 0, stream, h2b, Wgu, midb);
  hipLaunchKernelGGL(down_gemm, dim3(128, 4), dim3(256), 0, stream, midb, Wd, x2, out);
}

// Round 9
// 164.293 us; speedup vs baseline: 1.1664x; 1.0132x over previous
//
#include <hip/hip_runtime.h>
#include <hip/hip_bf16.h>
#include <math.h>

#define TT 2048
typedef __bf16 bf16x8 __attribute__((ext_vector_type(8)));
typedef float f32x4 __attribute__((ext_vector_type(4)));
typedef __hip_bfloat16 bf16;

static __device__ __forceinline__ f32x4 mfma16(bf16x8 a, bf16x8 b, f32x4 c) {
  return __builtin_amdgcn_mfma_f32_16x16x32_bf16(a, b, c, 0, 0, 0);
}
static __device__ __forceinline__ bf16x8 ldb8(const bf16* p) {
  return *(const bf16x8*)p;
}
static __device__ __forceinline__ unsigned short bfbits(float f) {
  bf16 b = __float2bfloat16(f);
  return *(unsigned short*)&b;
}
// async global->LDS, 16B per lane; lds base must be wave-uniform (HW adds lane*16)
static __device__ __forceinline__ void gll16(const bf16* g, bf16* l) {
  __builtin_amdgcn_global_load_lds(
      (const __attribute__((address_space(1))) unsigned int*)g,
      (__attribute__((address_space(3))) unsigned int*)l, 16, 0, 0);
}

// ---------------- fused weight convert/pack + attn RMSNorm ----------------
__global__ void __launch_bounds__(256) prep_kernel(
    const float* __restrict__ wq, const float* __restrict__ wk,
    const float* __restrict__ wv, const float* __restrict__ wo,
    const float* __restrict__ wg, const float* __restrict__ wu,
    const float* __restrict__ wd,
    bf16* __restrict__ Wqkv, bf16* __restrict__ Wo,
    bf16* __restrict__ Wgu, bf16* __restrict__ Wd,
    const float* __restrict__ x, const float* __restrict__ rmsw,
    bf16* __restrict__ hb) {
  if (blockIdx.x < 4096) {
    int idx = blockIdx.x * 256 + threadIdx.x;  // 0 .. 1048575
    if (idx < 196608) {                        // QKV pack
      int row = idx >> 8, col = idx & 255;
      const float* src = row < 256 ? wq : (row < 512 ? wk : wv);
      Wqkv[idx] = __float2bfloat16(src[(row & 255) * 256 + col]);
    } else if (idx < 262144) {
      int i = idx - 196608;
      Wo[i] = __float2bfloat16(wo[i]);
    } else if (idx < 786432) {                 // gate/up interleaved per 16 rows
      int i = idx - 262144;
      int row = i >> 8, col = i & 255;
      int t = row >> 4, r = row & 15;
      int f = (t >> 1) * 16 + r;
      const float* src = (t & 1) ? wu : wg;
      Wgu[i] = __float2bfloat16(src[f * 256 + col]);
    } else {
      int i = idx - 786432;
      Wd[i] = __float2bfloat16(wd[i]);
    }
  } else {
    const int wv_ = threadIdx.x >> 6, lane = threadIdx.x & 63;
    const int token = (blockIdx.x - 4096) * 4 + wv_;
    const float4 xv = ((const float4*)x)[token * 64 + lane];
    float ss = xv.x * xv.x + xv.y * xv.y + xv.z * xv.z + xv.w * xv.w;
#pragma unroll
    for (int off = 1; off < 64; off <<= 1) ss += __shfl_xor(ss, off, 64);
    const float inv = rsqrtf(ss * (1.0f / 256.0f) + 1e-5f);
    const float4 w4 = ((const float4*)rmsw)[lane];
    union { unsigned short u[4]; uint2 v2; } pk;
    pk.u[0] = bfbits(xv.x * inv * w4.x);
    pk.u[1] = bfbits(xv.y * inv * w4.y);
    pk.u[2] = bfbits(xv.z * inv * w4.z);
    pk.u[3] = bfbits(xv.w * inv * w4.w);
    ((uint2*)hb)[token * 64 + lane] = pk.v2;
  }
}

// ---------------- RMSNorm (1 wave per token) ----------------
__global__ void __launch_bounds__(256) rmsnorm_kernel(
    const float* __restrict__ x, const float* __restrict__ w, bf16* __restrict__ out) {
  const int wv = threadIdx.x >> 6, lane = threadIdx.x & 63;
  const int token = blockIdx.x * 4 + wv;
  const float4 xv = ((const float4*)x)[token * 64 + lane];
  float ss = xv.x * xv.x + xv.y * xv.y + xv.z * xv.z + xv.w * xv.w;
#pragma unroll
  for (int off = 1; off < 64; off <<= 1) ss += __shfl_xor(ss, off, 64);
  const float inv = rsqrtf(ss * (1.0f / 256.0f) + 1e-5f);
  const float4 w4 = ((const float4*)w)[lane];
  union { unsigned short u[4]; uint2 v2; } pk;
  pk.u[0] = bfbits(xv.x * inv * w4.x);
  pk.u[1] = bfbits(xv.y * inv * w4.y);
  pk.u[2] = bfbits(xv.z * inv * w4.z);
  pk.u[3] = bfbits(xv.w * inv * w4.w);
  ((uint2*)out)[token * 64 + lane] = pk.v2;
}

// ---------------- chunked-staging GEMM K-loop, SWAPPED operands ----------------
// Stages KC/32 sub-tiles [rows][32] per operand; one barrier pair per chunk.
// MFMA called as (B-frag, A-frag): D[row = B-row (n/f/o), hi*4+r][col = A-row
// (m), lo] -> each lane holds 4 CONSECUTIVE output cols for one m => packed
// vector epilogue stores.
template <int BM, int BN, int KC>
static __device__ __forceinline__ void gemm_chunks(
    const bf16* __restrict__ Ag, const bf16* __restrict__ Bg,
    int lda, int ldb, int ktot,
    bf16* ldsA, bf16* ldsB, int wave, int lane,
    f32x4 (&acc)[BM / 32][BN / 32]) {
  const int lo = lane & 15, hi = lane >> 4;
  const int wm = (wave >> 1) * (BM / 2), wn = (wave & 1) * (BN / 2);
  const int lrow = lane >> 2, lcol = (lane & 3) * 8;
  for (int kc = 0; kc < ktot; kc += KC) {
    __syncthreads();  // protect LDS reuse
#pragma unroll
    for (int c = 0; c < KC / 32; c++) {
      for (int is = wave; is < BM / 16; is += 4)
        gll16(Ag + (size_t)(is * 16 + lrow) * lda + kc + c * 32 + lcol,
              ldsA + c * (BM * 32) + is * 512);
      for (int is = wave; is < BN / 16; is += 4)
        gll16(Bg + (size_t)(is * 16 + lrow) * ldb + kc + c * 32 + lcol,
              ldsB + c * (BN * 32) + is * 512);
    }
    __syncthreads();  // staging complete (vmcnt drain once per chunk)
#pragma unroll
    for (int c = 0; c < KC / 32; c++) {
      bf16x8 af[BM / 32], bfr[BN / 32];
#pragma unroll
      for (int i = 0; i < BM / 32; i++)
        af[i] = ldb8(ldsA + c * (BM * 32) + (wm + i * 16 + lo) * 32 + hi * 8);
#pragma unroll
      for (int j = 0; j < BN / 32; j++)
        bfr[j] = ldb8(ldsB + c * (BN * 32) + (wn + j * 16 + lo) * 32 + hi * 8);
#pragma unroll
      for (int i = 0; i < BM / 32; i++)
#pragma unroll
        for (int j = 0; j < BN / 32; j++)
          acc[i][j] = mfma16(bfr[j], af[i], acc[i][j]);  // swapped
    }
  }
}

// ---------------- QKV GEMM: 128x64 tiles, KC=128, grid (64, 12) ----------------
// Swapped layout: lane holds 4 consecutive o for one token t -> packed b64
// q/k stores. V^T written kt-tiled: [bh][kt>>5][d][kt&31].
__global__ void __launch_bounds__(256) qkv_gemm(
    const bf16* __restrict__ A, const bf16* __restrict__ W,
    bf16* __restrict__ qb, bf16* __restrict__ kb, bf16* __restrict__ vtb) {
  __shared__ __align__(16) bf16 ldsA[128 * 128], ldsB[64 * 128];
  const int wave = threadIdx.x >> 6, lane = threadIdx.x & 63;
  const int lo = lane & 15, hi = lane >> 4;
  const int wm = (wave >> 1) * 64, wn = (wave & 1) * 32;
  f32x4 acc[4][2];
#pragma unroll
  for (int i = 0; i < 4; i++)
#pragma unroll
    for (int j = 0; j < 2; j++) acc[i][j] = (f32x4){0.f, 0.f, 0.f, 0.f};
  gemm_chunks<128, 64, 128>(A + (size_t)blockIdx.x * 128 * 256,
                            W + (size_t)blockIdx.y * 64 * 256,
                            256, 256, 256, ldsA, ldsB, wave, lane, acc);
#pragma unroll
  for (int i = 0; i < 4; i++) {
    const int m = blockIdx.x * 128 + wm + i * 16 + lo;
    const int b = m >> 11, t = m & (TT - 1);
#pragma unroll
    for (int j = 0; j < 2; j++) {
      const int o0 = blockIdx.y * 64 + wn + j * 16 + hi * 4;  // 4 consecutive o
      const int sel = o0 >> 8, hd = (o0 >> 6) & 3, d0 = o0 & 63;
      const int bh = b * 4 + hd;
      if (sel == 0) {
        union { unsigned short u[4]; uint2 v2; } pk;
#pragma unroll
        for (int r = 0; r < 4; r++) pk.u[r] = bfbits(acc[i][j][r] * 0.125f);
        *(uint2*)&qb[((size_t)bh * TT + t) * 64 + d0] = pk.v2;
      } else if (sel == 1) {
        union { unsigned short u[4]; uint2 v2; } pk;
#pragma unroll
        for (int r = 0; r < 4; r++) pk.u[r] = bfbits(acc[i][j][r]);
        *(uint2*)&kb[((size_t)bh * TT + t) * 64 + d0] = pk.v2;
      } else {
        bf16* vt = vtb + (size_t)bh * (64 * TT) + (t >> 5) * 2048 + (t & 31);
#pragma unroll
        for (int r = 0; r < 4; r++)
          vt[(d0 + r) * 32] = __float2bfloat16(acc[i][j][r]);
      }
    }
  }
}

// ---------------- flash attention v5: paired qt, kt-tiled V^T ----------------
// Swapped-operand MFMA (A=K, B=Q -> S^T), packed b64 LDS P-writes, no-max
// softmax (scores bounded ~12.5). qt-pairing: block does tiles qtp and
// 63-qtp => all 512 blocks do exactly 65 steps. V^T kt-tiled (coalesced).
__global__ void __launch_bounds__(256) attn_kernel(
    const bf16* __restrict__ qbp, const bf16* __restrict__ kbp,
    const bf16* __restrict__ vtp, bf16* __restrict__ aout) {
  const int wave = threadIdx.x >> 6, lane = threadIdx.x & 63;
  const int lo = lane & 15, hi = lane >> 4;
  const int bh = blockIdx.y;
  __shared__ __align__(16) unsigned short ldsP[4][2][16][40];  // P^T per wave/mf
  __shared__ __align__(16) unsigned short ldsO[4][32][88];     // bf16 partial O
  __shared__ float ldsL[4][2][16];
  const bf16* Q  = qbp + (size_t)bh * (TT * 64);
  const bf16* Kp = kbp + (size_t)bh * (TT * 64);
  const bf16* Vt = vtp + (size_t)bh * (64 * TT);
  const int b = bh >> 2, hd = bh & 3;

  for (int half = 0; half < 2; half++) {
    const int qt = half == 0 ? (int)blockIdx.x : 63 - (int)blockIdx.x;
    const int q0 = qt * 32;
    const int ns = qt + 1;
    bf16x8 aq[2][2];
#pragma unroll
    for (int mf = 0; mf < 2; mf++)
#pragma unroll
      for (int h = 0; h < 2; h++)
        aq[mf][h] = ldb8(Q + (q0 + mf * 16 + lo) * 64 + h * 32 + hi * 8);
    f32x4 acc[2][4];
#pragma unroll
    for (int mf = 0; mf < 2; mf++)
#pragma unroll
      for (int dt = 0; dt < 4; dt++) acc[mf][dt] = (f32x4){0.f, 0.f, 0.f, 0.f};
    float lsum[2] = {0.f, 0.f};

    int i = wave;
    bf16x8 kf[2][2];
    if (i < ns) {
#pragma unroll
      for (int ct = 0; ct < 2; ct++) {
        const bf16* kr = Kp + (i * 32 + ct * 16 + lo) * 64 + hi * 8;
        kf[ct][0] = ldb8(kr);
        kf[ct][1] = ldb8(kr + 32);
      }
    }
    for (; i < ns; i += 4) {
      const int kt0 = i * 32;
      // QK^T swapped: S^T[kt][q]; lane: q = q0+mf*16+lo, kt = kt0+ct*16+hi*4+r
      f32x4 s[2][2];
#pragma unroll
      for (int mf = 0; mf < 2; mf++)
#pragma unroll
        for (int ct = 0; ct < 2; ct++) {
          f32x4 sc = (f32x4){0.f, 0.f, 0.f, 0.f};
          sc = mfma16(kf[ct][0], aq[mf][0], sc);
          sc = mfma16(kf[ct][1], aq[mf][1], sc);
          s[mf][ct] = sc;
        }
      // prefetch this wave's next K step (clamped re-load on last iter)
      const int ktn = (i + 4 < ns ? i + 4 : i) * 32;
      bf16x8 kn[2][2];
#pragma unroll
      for (int ct = 0; ct < 2; ct++) {
        const bf16* kr = Kp + (ktn + ct * 16 + lo) * 64 + hi * 8;
        kn[ct][0] = ldb8(kr);
        kn[ct][1] = ldb8(kr + 32);
      }
      // V loads (kt-tiled: contiguous 4KB tile), ahead of the exp section
      const bf16* vtile = Vt + i * 2048;
      bf16x8 vb[4];
#pragma unroll
      for (int dt = 0; dt < 4; dt++)
        vb[dt] = ldb8(vtile + (dt * 16 + lo) * 32 + hi * 8);
      if (i == ns - 1) {  // diagonal step: causal mask
#pragma unroll
        for (int mf = 0; mf < 2; mf++)
#pragma unroll
          for (int ct = 0; ct < 2; ct++)
#pragma unroll
            for (int r = 0; r < 4; r++)
              if (kt0 + ct * 16 + hi * 4 + r > q0 + mf * 16 + lo) s[mf][ct][r] = -INFINITY;
      }
#pragma unroll
      for (int mf = 0; mf < 2; mf++)
#pragma unroll
        for (int ct = 0; ct < 2; ct++) {
          union { unsigned short u[4]; uint2 v2; } pk;
#pragma unroll
          for (int r = 0; r < 4; r++) {
            const float p = __expf(s[mf][ct][r]);  // exp(-inf)=0 handles mask
            lsum[mf] += p;
            pk.u[r] = bfbits(p);
          }
          *(uint2*)&ldsP[wave][mf][lo][ct * 16 + hi * 4] = pk.v2;
        }
      // intra-wave LDS write->read ordering only (waves independent here)
      asm volatile("s_waitcnt lgkmcnt(0)" ::: "memory");
      bf16x8 pa[2];
#pragma unroll
      for (int mf = 0; mf < 2; mf++)
        pa[mf] = *(const bf16x8*)&ldsP[wave][mf][lo][hi * 8];
      // O^T = V^T x P^T: lane: d = dt*16+hi*4+r, q = q0+mf*16+lo
#pragma unroll
      for (int mf = 0; mf < 2; mf++)
#pragma unroll
        for (int dt = 0; dt < 4; dt++)
          acc[mf][dt] = mfma16(vb[dt], pa[mf], acc[mf][dt]);
#pragma unroll
      for (int ct = 0; ct < 2; ct++) {
        kf[ct][0] = kn[ct][0];
        kf[ct][1] = kn[ct][1];
      }
    }

    // reduce lsum across the 4 hi replicas
#pragma unroll
    for (int mf = 0; mf < 2; mf++) {
      lsum[mf] += __shfl_xor(lsum[mf], 16, 64);
      lsum[mf] += __shfl_xor(lsum[mf], 32, 64);
    }
    if (hi == 0) {
      ldsL[wave][0][lo] = lsum[0];
      ldsL[wave][1][lo] = lsum[1];
    }
    // publish bf16 partial O^T: lane packs 4 consecutive d for its q
#pragma unroll
    for (int mf = 0; mf < 2; mf++)
#pragma unroll
      for (int dt = 0; dt < 4; dt++) {
        union { unsigned short u[4]; uint2 v2; } pk;
#pragma unroll
        for (int r = 0; r < 4; r++) pk.u[r] = bfbits(acc[mf][dt][r]);
        *(uint2*)&ldsO[wave][mf * 16 + lo][dt * 16 + hi * 4] = pk.v2;
      }
    __syncthreads();

    // combine: thread t owns q row t>>3, d-slice ((t&7)*8 .. +7)
    const int q = threadIdx.x >> 3;
    const int d0 = (threadIdx.x & 7) * 8;
    const float L = ldsL[0][q >> 4][q & 15] + ldsL[1][q >> 4][q & 15] +
                    ldsL[2][q >> 4][q & 15] + ldsL[3][q >> 4][q & 15];
    float o[8] = {0.f, 0.f, 0.f, 0.f, 0.f, 0.f, 0.f, 0.f};
#pragma unroll
    for (int w = 0; w < 4; w++) {
      const bf16x8 v = *(const bf16x8*)&ldsO[w][q][d0];
#pragma unroll
      for (int j = 0; j < 8; j++) o[j] += (float)v[j];
    }
    const float invL = 1.0f / L;
    bf16* dst = aout + ((size_t)(b * TT + q0 + q)) * 256 + hd * 64 + d0;
    union { unsigned short u[8]; uint4 v4; } pk;
#pragma unroll
    for (int j = 0; j < 8; j++) pk.u[j] = bfbits(o[j] * invL);
    *(uint4*)dst = pk.v4;
    __syncthreads();  // ldsO/ldsL reused by next half
  }
}

// ---------------- WO GEMM + residual: 64x64, KC=256, grid (128,4) ----------------
// Swapped layout: lane holds 4 consecutive cols for one m -> float4 I/O.
__global__ void __launch_bounds__(256) wo_gemm(
    const bf16* __restrict__ A, const bf16* __restrict__ W,
    const float* __restrict__ x, float* __restrict__ x2) {
  __shared__ __align__(16) bf16 ldsA[64 * 256], ldsB[64 * 256];
  const int wave = threadIdx.x >> 6, lane = threadIdx.x & 63;
  const int lo = lane & 15, hi = lane >> 4;
  const int wm = (wave >> 1) * 32, wn = (wave & 1) * 32;
  f32x4 acc[2][2];
#pragma unroll
  for (int i = 0; i < 2; i++)
#pragma unroll
    for (int j = 0; j < 2; j++) acc[i][j] = (f32x4){0.f, 0.f, 0.f, 0.f};
  gemm_chunks<64, 64, 256>(A + (size_t)blockIdx.x * 64 * 256,
                           W + (size_t)blockIdx.y * 64 * 256,
                           256, 256, 256, ldsA, ldsB, wave, lane, acc);
#pragma unroll
  for (int i = 0; i < 2; i++) {
    const int m = blockIdx.x * 64 + wm + i * 16 + lo;
#pragma unroll
    for (int j = 0; j < 2; j++) {
      const int col0 = blockIdx.y * 64 + wn + j * 16 + hi * 4;
      const size_t idx = (size_t)m * 256 + col0;
      const float4 xv = *(const float4*)&x[idx];
      float4 ov;
      ov.x = xv.x + acc[i][j][0];
      ov.y = xv.y + acc[i][j][1];
      ov.z = xv.z + acc[i][j][2];
      ov.w = xv.w + acc[i][j][3];
      *(float4*)&x2[idx] = ov;
    }
  }
}

// ---------------- gate/up GEMM + SiLU: 128x128, KC=64, grid (64, 16) ----------------
// KC=64: 32 KB LDS -> 4 blocks/CU. Swapped layout: lane holds 4 consecutive f
// for one m -> packed b64 stores.
__global__ void __launch_bounds__(256) gu_gemm(
    const bf16* __restrict__ A, const bf16* __restrict__ W, bf16* __restrict__ mid) {
  __shared__ __align__(16) bf16 ldsA[128 * 64], ldsB[128 * 64];
  const int wave = threadIdx.x >> 6, lane = threadIdx.x & 63;
  const int lo = lane & 15, hi = lane >> 4;
  const int wm = (wave >> 1) * 64, wn = (wave & 1) * 64;
  f32x4 acc[4][4];
#pragma unroll
  for (int i = 0; i < 4; i++)
#pragma unroll
    for (int j = 0; j < 4; j++) acc[i][j] = (f32x4){0.f, 0.f, 0.f, 0.f};
  gemm_chunks<128, 128, 64>(A + (size_t)blockIdx.x * 128 * 256,
                            W + (size_t)blockIdx.y * 128 * 256,
                            256, 256, 256, ldsA, ldsB, wave, lane, acc);
  const int B0 = blockIdx.y * 128 + wn;  // Wgu row base for this wave
#pragma unroll
  for (int i = 0; i < 4; i++) {
    const int m = blockIdx.x * 128 + wm + i * 16 + lo;
#pragma unroll
    for (int p = 0; p < 2; p++) {
      // j=2p: gate rows, j=2p+1: up rows (Wgu 16-row interleave); D-row = f
      const int f0 = ((B0 >> 5) + p) * 16 + hi * 4;
      union { unsigned short u[4]; uint2 v2; } pk;
#pragma unroll
      for (int r = 0; r < 4; r++) {
        const float g = acc[i][2 * p][r];
        const float u = acc[i][2 * p + 1][r];
        pk.u[r] = bfbits(g / (1.f + __expf(-g)) * u);
      }
      *(uint2*)&mid[(size_t)m * 1024 + f0] = pk.v2;
    }
  }
}

// ---------------- down GEMM + residual: 64x64, KC=256, grid (128,4) ------
__global__ void __launch_bounds__(256) down_gemm(
    const bf16* __restrict__ A, const bf16* __restrict__ W,
    const float* __restrict__ x2, float* __restrict__ out) {
  __shared__ __align__(16) bf16 ldsA[64 * 256], ldsB[64 * 256];
  const int wave = threadIdx.x >> 6, lane = threadIdx.x & 63;
  const int lo = lane & 15, hi = lane >> 4;
  const int wm = (wave >> 1) * 32, wn = (wave & 1) * 32;
  f32x4 acc[2][2];
#pragma unroll
  for (int i = 0; i < 2; i++)
#pragma unroll
    for (int j = 0; j < 2; j++) acc[i][j] = (f32x4){0.f, 0.f, 0.f, 0.f};
  gemm_chunks<64, 64, 256>(A + (size_t)blockIdx.x * 64 * 1024,
                           W + (size_t)blockIdx.y * 64 * 1024,
                           1024, 1024, 1024, ldsA, ldsB, wave, lane, acc);
#pragma unroll
  for (int i = 0; i < 2; i++) {
    const int m = blockIdx.x * 64 + wm + i * 16 + lo;
#pragma unroll
    for (int j = 0; j < 2; j++) {
      const int col0 = blockIdx.y * 64 + wn + j * 16 + hi * 4;
      const size_t idx = (size_t)m * 256 + col0;
      const float4 xv = *(const float4*)&x2[idx];
      float4 ov;
      ov.x = xv.x + acc[i][j][0];
      ov.y = xv.y + acc[i][j][1];
      ov.z = xv.z + acc[i][j][2];
      ov.w = xv.w + acc[i][j][3];
      *(float4*)&out[idx] = ov;
    }
  }
}

extern "C" void kernel_launch(void* const* d_in, const int* in_sizes, int n_in,
                              void* d_out, int out_size, void* d_ws, size_t ws_size,
                              hipStream_t stream) {
  const float* x          = (const float*)d_in[0];
  const float* rms_attn_w = (const float*)d_in[2];
  const float* wq         = (const float*)d_in[3];
  const float* wk         = (const float*)d_in[4];
  const float* wv         = (const float*)d_in[5];
  const float* wo         = (const float*)d_in[6];
  const float* rms_ffn_w  = (const float*)d_in[7];
  const float* wg         = (const float*)d_in[8];
  const float* wu         = (const float*)d_in[9];
  const float* wd         = (const float*)d_in[10];
  float* out = (float*)d_out;
  char* ws = (char*)d_ws;

  bf16* Wqkv  = (bf16*)(ws + 0);
  bf16* Wo    = (bf16*)(ws + 393216);
  bf16* Wgu   = (bf16*)(ws + 524288);
  bf16* Wd    = (bf16*)(ws + 1572864);
  bf16* hb    = (bf16*)(ws + 2097152);
  bf16* qb    = (bf16*)(ws + 6291456);
  bf16* kb    = (bf16*)(ws + 10485760);
  bf16* vtb   = (bf16*)(ws + 14680064);
  bf16* attnb = (bf16*)(ws + 18874368);
  float* x2   = (float*)(ws + 23068672);
  bf16* h2b   = (bf16*)(ws + 31457280);
  bf16* midb  = (bf16*)(ws + 35651584);

  hipLaunchKernelGGL(prep_kernel, dim3(6144), dim3(256), 0, stream,
                     wq, wk, wv, wo, wg, wu, wd, Wqkv, Wo, Wgu, Wd,
                     x, rms_attn_w, hb);
  hipLaunchKernelGGL(qkv_gemm, dim3(64, 12), dim3(256), 0, stream, hb, Wqkv, qb, kb, vtb);
  hipLaunchKernelGGL(attn_kernel, dim3(32, 16), dim3(256), 0, stream, qb, kb, vtb, attnb);
  hipLaunchKernelGGL(wo_gemm, dim3(128, 4), dim3(256), 0, stream, attnb, Wo, x, x2);
  hipLaunchKernelGGL(rmsnorm_kernel, dim3(2048), dim3(256), 0, stream, x2, rms_ffn_w, h2b);
  hipLaunchKernelGGL(gu_gemm, dim3(64, 16), dim3(256), 0, stream, h2b, Wgu, midb);
  hipLaunchKernelGGL(down_gemm, dim3(128, 4), dim3(256), 0, stream, midb, Wd, x2, out);
}